// Round 1
// baseline (164.257 us; speedup 1.0000x reference)
//
#include <hip/hip_runtime.h>

#define CHN 96
#define IMG_H 256
#define IMG_W 256
#define ROWS_PER_BLOCK 8   // 8 waves of 64 lanes, one row per wave

// One wave = one output row: 64 lanes x float4 = 256 px.
// Halo (x-1 / x+4) comes from wave shuffles; y-halo from extra row loads
// that hit L1 (shared across the block's 8 waves).
__global__ __launch_bounds__(ROWS_PER_BLOCK * 64)
void sharpen3x3_dw(const float* __restrict__ x,
                   const float* __restrict__ kern,
                   float* __restrict__ out)
{
    const int lane = threadIdx.x & 63;
    const int wave = threadIdx.x >> 6;

    const int groups_per_img = IMG_H / ROWS_PER_BLOCK;           // 32
    const int img  = blockIdx.x / groups_per_img;                // n*CHN + c
    const int grp  = blockIdx.x % groups_per_img;
    const int c    = img % CHN;
    const int y    = grp * ROWS_PER_BLOCK + wave;

    // Per-channel 3x3 stencil: diagonal block of the dense (C,C,3,3) kernel.
    const float* kw = kern + ((size_t)c * CHN + c) * 9;
    float w0 = kw[0], w1 = kw[1], w2 = kw[2];
    float w3 = kw[3], w4 = kw[4], w5 = kw[5];
    float w6 = kw[6], w7 = kw[7], w8 = kw[8];

    const float* xplane = x + (size_t)img * IMG_H * IMG_W;

    float acc0 = 0.f, acc1 = 0.f, acc2 = 0.f, acc3 = 0.f;

    #pragma unroll
    for (int ky = 0; ky < 3; ++ky) {
        const int yy = y + ky - 1;           // wave-uniform branch
        float4 v = make_float4(0.f, 0.f, 0.f, 0.f);
        if (yy >= 0 && yy < IMG_H) {
            v = *(const float4*)(xplane + (size_t)yy * IMG_W + 4 * lane);
        }
        // left neighbor = previous lane's v.w ; right = next lane's v.x
        float l = __shfl_up(v.w, 1);
        float r = __shfl_down(v.x, 1);
        if (lane == 0)  l = 0.f;   // x = -1  zero pad
        if (lane == 63) r = 0.f;   // x = 256 zero pad

        float ka, kb, kc;
        if      (ky == 0) { ka = w0; kb = w1; kc = w2; }
        else if (ky == 1) { ka = w3; kb = w4; kc = w5; }
        else              { ka = w6; kb = w7; kc = w8; }

        acc0 += ka * l   + kb * v.x + kc * v.y;
        acc1 += ka * v.x + kb * v.y + kc * v.z;
        acc2 += ka * v.y + kb * v.z + kc * v.w;
        acc3 += ka * v.z + kb * v.w + kc * r;
    }

    float4 o = make_float4(acc0, acc1, acc2, acc3);
    *(float4*)(out + ((size_t)img * IMG_H + y) * IMG_W + 4 * lane) = o;
}

extern "C" void kernel_launch(void* const* d_in, const int* in_sizes, int n_in,
                              void* d_out, int out_size, void* d_ws, size_t ws_size,
                              hipStream_t stream) {
    const float* x    = (const float*)d_in[0];
    const float* kern = (const float*)d_in[1];
    float* out        = (float*)d_out;

    const int n_imgs = 16 * CHN;                       // 1536 (n,c) planes
    const int grid   = n_imgs * (IMG_H / ROWS_PER_BLOCK); // 49152 blocks

    hipLaunchKernelGGL(sharpen3x3_dw, dim3(grid), dim3(ROWS_PER_BLOCK * 64),
                       0, stream, x, kern, out);
}

// Round 2
// 158.867 us; speedup vs baseline: 1.0339x; 1.0339x over previous
//
#include <hip/hip_runtime.h>

#define CHN 96
#define IMG_H 256
#define IMG_W 256
#define STRIP 64          // rows per wave
#define WPB 8             // waves per block

typedef float vfloat4 __attribute__((ext_vector_type(4)));

struct Row { float l, x, y, z, w, r; };

__device__ __forceinline__ Row mkrow(vfloat4 v, int lane) {
    Row r;
    r.x = v.x; r.y = v.y; r.z = v.z; r.w = v.w;
    r.l = __shfl_up(v.w, 1);
    r.r = __shfl_down(v.x, 1);
    if (lane == 0)  r.l = 0.f;   // x = -1 zero pad
    if (lane == 63) r.r = 0.f;   // x = 256 zero pad
    return r;
}

__device__ __forceinline__ vfloat4 stencil(const Row& a, const Row& b, const Row& c,
                                           float w0, float w1, float w2,
                                           float w3, float w4, float w5,
                                           float w6, float w7, float w8) {
    vfloat4 o;
    o.x = w0*a.l + w1*a.x + w2*a.y
        + w3*b.l + w4*b.x + w5*b.y
        + w6*c.l + w7*c.x + w8*c.y;
    o.y = w0*a.x + w1*a.y + w2*a.z
        + w3*b.x + w4*b.y + w5*b.z
        + w6*c.x + w7*c.y + w8*c.z;
    o.z = w0*a.y + w1*a.z + w2*a.w
        + w3*b.y + w4*b.z + w5*b.w
        + w6*c.y + w7*c.z + w8*c.w;
    o.w = w0*a.z + w1*a.w + w2*a.r
        + w3*b.z + w4*b.w + w5*b.r
        + w6*c.z + w7*c.w + w8*c.r;
    return o;
}

__global__ __launch_bounds__(WPB * 64)
void sharpen3x3_strip(const float* __restrict__ x,
                      const float* __restrict__ kern,
                      float* __restrict__ out)
{
    const int lane = threadIdx.x & 63;
    const int wave = threadIdx.x >> 6;

    const int strip_id = blockIdx.x * WPB + wave;            // 0..6143
    const int spp      = IMG_H / STRIP;                      // strips per plane = 4
    const int plane    = strip_id / spp;                     // n*CHN + c
    const int sy       = (strip_id % spp) * STRIP;           // first output row
    const int c        = plane % CHN;

    // diagonal 3x3 block of the dense (C,C,3,3) kernel
    const float* kw = kern + ((size_t)c * CHN + c) * 9;
    const float w0 = kw[0], w1 = kw[1], w2 = kw[2];
    const float w3 = kw[3], w4 = kw[4], w5 = kw[5];
    const float w6 = kw[6], w7 = kw[7], w8 = kw[8];

    const float* xp = x   + (size_t)plane * IMG_H * IMG_W;
    float*       op = out + (size_t)plane * IMG_H * IMG_W;

    const int col = 4 * lane;

    Row prev, cur;
    if (sy == 0) {
        prev = Row{0.f, 0.f, 0.f, 0.f, 0.f, 0.f};
    } else {
        vfloat4 vp = *(const vfloat4*)(xp + (size_t)(sy - 1) * IMG_W + col);
        prev = mkrow(vp, lane);
    }
    {
        vfloat4 vc = *(const vfloat4*)(xp + (size_t)sy * IMG_W + col);
        cur = mkrow(vc, lane);
    }

    for (int i = 0; i < STRIP; i += 4) {
        const int y = sy + i;
        const float* base = xp + (size_t)(y + 1) * IMG_W + col;

        // issue all 4 row loads before any use (4 outstanding dwordx4 / lane)
        vfloat4 v0 = *(const vfloat4*)(base);
        vfloat4 v1 = *(const vfloat4*)(base + IMG_W);
        vfloat4 v2 = *(const vfloat4*)(base + 2 * IMG_W);
        vfloat4 v3;
        const bool last = (y + 4 >= IMG_H);                  // wave-uniform
        if (!last) v3 = *(const vfloat4*)(base + 3 * IMG_W);
        else       v3 = (vfloat4){0.f, 0.f, 0.f, 0.f};

        Row n0 = mkrow(v0, lane);
        Row n1 = mkrow(v1, lane);
        Row n2 = mkrow(v2, lane);
        Row n3 = last ? Row{0.f,0.f,0.f,0.f,0.f,0.f} : mkrow(v3, lane);

        vfloat4 o0 = stencil(prev, cur, n0, w0,w1,w2,w3,w4,w5,w6,w7,w8);
        vfloat4 o1 = stencil(cur,  n0,  n1, w0,w1,w2,w3,w4,w5,w6,w7,w8);
        vfloat4 o2 = stencil(n0,   n1,  n2, w0,w1,w2,w3,w4,w5,w6,w7,w8);
        vfloat4 o3 = stencil(n1,   n2,  n3, w0,w1,w2,w3,w4,w5,w6,w7,w8);

        float* ob = op + (size_t)y * IMG_W + col;
        __builtin_nontemporal_store(o0, (vfloat4*)(ob));
        __builtin_nontemporal_store(o1, (vfloat4*)(ob + IMG_W));
        __builtin_nontemporal_store(o2, (vfloat4*)(ob + 2 * IMG_W));
        __builtin_nontemporal_store(o3, (vfloat4*)(ob + 3 * IMG_W));

        prev = n2;
        cur  = n3;
    }
}

extern "C" void kernel_launch(void* const* d_in, const int* in_sizes, int n_in,
                              void* d_out, int out_size, void* d_ws, size_t ws_size,
                              hipStream_t stream) {
    const float* x    = (const float*)d_in[0];
    const float* kern = (const float*)d_in[1];
    float* out        = (float*)d_out;

    const int n_strips = 16 * CHN * (IMG_H / STRIP);   // 6144 waves
    const int grid     = n_strips / WPB;               // 768 blocks

    hipLaunchKernelGGL(sharpen3x3_strip, dim3(grid), dim3(WPB * 64),
                       0, stream, x, kern, out);
}

// Round 3
// 153.828 us; speedup vs baseline: 1.0678x; 1.0328x over previous
//
#include <hip/hip_runtime.h>

#define CHN 96
#define IMG_H 256
#define IMG_W 256
#define STRIP 64          // rows per wave
#define WPB 8             // waves per block
#define GRP 8             // rows per pipelined group

typedef float vfloat4 __attribute__((ext_vector_type(4)));

struct Row { float l, x, y, z, w, r; };

__device__ __forceinline__ Row mkrow(vfloat4 v, int lane) {
    Row r;
    r.x = v.x; r.y = v.y; r.z = v.z; r.w = v.w;
    r.l = __shfl_up(v.w, 1);
    r.r = __shfl_down(v.x, 1);
    if (lane == 0)  r.l = 0.f;   // x = -1 zero pad
    if (lane == 63) r.r = 0.f;   // x = 256 zero pad
    return r;
}

__device__ __forceinline__ vfloat4 ldrow(const float* xp, int yy, int col) {
    // yy >= 0 guaranteed by callers; zero-fill past the bottom edge.
    if (yy < IMG_H)
        return __builtin_nontemporal_load(
            (const vfloat4*)(xp + (size_t)yy * IMG_W + col));
    return (vfloat4){0.f, 0.f, 0.f, 0.f};
}

__device__ __forceinline__ vfloat4 stencil(const Row& a, const Row& b, const Row& c,
                                           float w0, float w1, float w2,
                                           float w3, float w4, float w5,
                                           float w6, float w7, float w8) {
    vfloat4 o;
    o.x = w0*a.l + w1*a.x + w2*a.y
        + w3*b.l + w4*b.x + w5*b.y
        + w6*c.l + w7*c.x + w8*c.y;
    o.y = w0*a.x + w1*a.y + w2*a.z
        + w3*b.x + w4*b.y + w5*b.z
        + w6*c.x + w7*c.y + w8*c.z;
    o.z = w0*a.y + w1*a.z + w2*a.w
        + w3*b.y + w4*b.z + w5*b.w
        + w6*c.y + w7*c.z + w8*c.w;
    o.w = w0*a.z + w1*a.w + w2*a.r
        + w3*b.z + w4*b.w + w5*b.r
        + w6*c.z + w7*c.w + w8*c.r;
    return o;
}

__global__ __launch_bounds__(WPB * 64)
void sharpen3x3_pipe(const float* __restrict__ x,
                     const float* __restrict__ kern,
                     float* __restrict__ out)
{
    const int lane = threadIdx.x & 63;
    const int wave = threadIdx.x >> 6;

    const int strip_id = blockIdx.x * WPB + wave;            // 0..6143
    const int spp      = IMG_H / STRIP;                      // strips per plane = 4
    const int plane    = strip_id / spp;                     // n*CHN + c
    const int sy       = (strip_id % spp) * STRIP;           // first output row
    const int c        = plane % CHN;

    // diagonal 3x3 block of the dense (C,C,3,3) kernel
    const float* kw = kern + ((size_t)c * CHN + c) * 9;
    const float w0 = kw[0], w1 = kw[1], w2 = kw[2];
    const float w3 = kw[3], w4 = kw[4], w5 = kw[5];
    const float w6 = kw[6], w7 = kw[7], w8 = kw[8];

    const float* xp = x   + (size_t)plane * IMG_H * IMG_W;
    float*       op = out + (size_t)plane * IMG_H * IMG_W;

    const int col = 4 * lane;

    Row prev, cur;
    if (sy == 0) {
        prev = Row{0.f, 0.f, 0.f, 0.f, 0.f, 0.f};
    } else {
        prev = mkrow(ldrow(xp, sy - 1, col), lane);
    }
    cur = mkrow(ldrow(xp, sy, col), lane);

    // prime the pipeline: group 0 input rows sy+1 .. sy+GRP
    vfloat4 va[GRP];
    #pragma unroll
    for (int j = 0; j < GRP; ++j) va[j] = ldrow(xp, sy + 1 + j, col);

    #pragma unroll 1
    for (int g = 0; g < STRIP / GRP; ++g) {
        const int y = sy + g * GRP;

        // issue next group's loads BEFORE consuming the current group
        vfloat4 vb[GRP];
        if (g + 1 < STRIP / GRP) {
            #pragma unroll
            for (int j = 0; j < GRP; ++j)
                vb[j] = ldrow(xp, y + GRP + 1 + j, col);
        } else {
            #pragma unroll
            for (int j = 0; j < GRP; ++j)
                vb[j] = (vfloat4){0.f, 0.f, 0.f, 0.f};
        }

        // compute current group (rows y .. y+GRP-1)
        #pragma unroll
        for (int j = 0; j < GRP; ++j) {
            Row n = mkrow(va[j], lane);          // input row y+j+1 (zero past edge)
            vfloat4 o = stencil(prev, cur, n,
                                w0,w1,w2,w3,w4,w5,w6,w7,w8);
            __builtin_nontemporal_store(
                o, (vfloat4*)(op + (size_t)(y + j) * IMG_W + col));
            prev = cur;
            cur  = n;
        }

        #pragma unroll
        for (int j = 0; j < GRP; ++j) va[j] = vb[j];
    }
}

extern "C" void kernel_launch(void* const* d_in, const int* in_sizes, int n_in,
                              void* d_out, int out_size, void* d_ws, size_t ws_size,
                              hipStream_t stream) {
    const float* x    = (const float*)d_in[0];
    const float* kern = (const float*)d_in[1];
    float* out        = (float*)d_out;

    const int n_strips = 16 * CHN * (IMG_H / STRIP);   // 6144 waves
    const int grid     = n_strips / WPB;               // 768 blocks

    hipLaunchKernelGGL(sharpen3x3_pipe, dim3(grid), dim3(WPB * 64),
                       0, stream, x, kern, out);
}